// Round 11
// baseline (337.949 us; speedup 1.0000x reference)
//
#include <hip/hip_runtime.h>
#include <hip/hip_bf16.h>
#include <hip/hip_fp16.h>
#include <cstddef>
#include <cstdint>

// ---------------------------------------------------------------------------
// GAT 3-layer network. R11: aggregate gather restructured to break the
// srcs->payload dependency chain — bulk-load 16 srcs, then issue all es/h
// gathers independently (2 latency steps per 16 edges instead of 4-8).
// ---------------------------------------------------------------------------

typedef _Float16 half8 __attribute__((ext_vector_type(8)));
typedef _Float16 half4v __attribute__((ext_vector_type(4)));
typedef float floatx4 __attribute__((ext_vector_type(4)));

#define AS1(p) ((const __attribute__((address_space(1))) void*)(p))
#define AS3(p) ((__attribute__((address_space(3))) void*)(p))

__device__ __forceinline__ float leaky_exp(float e) {
    e = (e > 0.f) ? e : 0.2f * e;
    return __expf(e);
}

// ---------------- CSR build ----------------

__global__ void count_deg(const int* __restrict__ dst, int* __restrict__ deg, int E) {
    int e = blockIdx.x * blockDim.x + threadIdx.x;
    if (e < E) atomicAdd(&deg[dst[e]], 1);
}

__global__ void scan_kernel(const int* __restrict__ deg, int* __restrict__ row_start,
                            int* __restrict__ cursor, int n) {
    __shared__ int wsum[16];
    __shared__ int carry_s;
    int tid = threadIdx.x;              // 1024
    int wave = tid >> 6, lane = tid & 63;
    if (tid == 0) { carry_s = 0; row_start[0] = 0; }
    __syncthreads();
    for (int base = 0; base < n; base += 1024) {
        int i = base + tid;
        int v = (i < n) ? deg[i] : 0;
        int x = v;
#pragma unroll
        for (int off = 1; off < 64; off <<= 1) {
            int t = __shfl_up(x, off);
            if (lane >= off) x += t;
        }
        if (lane == 63) wsum[wave] = x;
        __syncthreads();
        if (wave == 0 && lane < 16) {
            int w = wsum[lane];
#pragma unroll
            for (int off = 1; off < 16; off <<= 1) {
                int t = __shfl_up(w, off);
                if (lane >= off) w += t;
            }
            wsum[lane] = w;
        }
        __syncthreads();
        int carry = carry_s;
        int incl = x + (wave ? wsum[wave - 1] : 0) + carry;
        if (i < n) { row_start[i + 1] = incl; cursor[i] = incl - v; }
        __syncthreads();
        if (tid == 1023) carry_s = incl;
        __syncthreads();
    }
}

__global__ void scatter_edges(const int* __restrict__ src, const int* __restrict__ dst,
                              int* __restrict__ cursor, int* __restrict__ srcs, int E) {
    int e = blockIdx.x * blockDim.x + threadIdx.x;
    if (e < E) {
        int p = atomicAdd(&cursor[dst[e]], 1);
        srcs[p] = src[e];
    }
}

// ---------------- merged prep: cast + weight transposes + attn projections --

__global__ void prep_all(const float* __restrict__ graph, _Float16* __restrict__ Ah, int n4,
                         int cb,
                         const float* __restrict__ W1, const float* __restrict__ W2,
                         const float* __restrict__ W3,
                         _Float16* __restrict__ Wt1, _Float16* __restrict__ Wt2,
                         _Float16* __restrict__ Bt3,
                         const float* __restrict__ as1, const float* __restrict__ ad1,
                         const float* __restrict__ as2, const float* __restrict__ ad2,
                         const float* __restrict__ as3, const float* __restrict__ ad3,
                         float* __restrict__ wes3, float* __restrict__ wed3) {
    int b = blockIdx.x;
    int tid = threadIdx.x;              // 256
    if (b < cb) {                       // ---- cast graph -> f16 ----
        int i = b * 256 + tid;
        if (i < n4) {
            float4 v = ((const float4*)graph)[i];
            half4v o = {(_Float16)v.x, (_Float16)v.y, (_Float16)v.z, (_Float16)v.w};
            ((half4v*)Ah)[i] = o;
        }
        return;
    }
    if (b < cb + 1024) {                // ---- transpose-cast weights ----
        __shared__ float t[32][33];
        int bb = b - cb;
        int region = bb >> 8, idx = bb & 255;
        int r0 = (idx >> 4) * 32, c0 = (idx & 15) * 32;
        const float* in;
        _Float16* out;
        int in_ld, out_ld;
        if (region == 0)      { in = W1;       out = Wt1;       in_ld = 512;  out_ld = 512;  }
        else if (region == 1) { in = W2;       out = Wt2;       in_ld = 512;  out_ld = 512;  }
        else if (region == 2) { in = W3;       out = Bt3;       in_ld = 1024; out_ld = 1024; }
        else                  { in = W3 + 512; out = Bt3 + 512; in_ld = 1024; out_ld = 1024; }
        int tx = tid & 31, ty = tid >> 5;   // 32 x 8
        for (int i = ty; i < 32; i += 8)
            t[i][tx] = in[(size_t)(r0 + i) * in_ld + c0 + tx];
        __syncthreads();
        for (int i = ty; i < 32; i += 8)
            out[(size_t)(c0 + i) * out_ld + r0 + tx] = (_Float16)t[tx][i];
        return;
    }
    // ---- attention projections ----
    int w = (b - cb - 1024) * 4 + (tid >> 6);
    int lane = tid & 63;
    if (w < 8192) {                       // Wt1/Wt2 attn rows: 2 layers x 2 sel x 4 h x 512 d
        int layer = w >> 12;
        int idx = w & 4095;
        int d = idx & 511, hh = (idx >> 9) & 3, sel = idx >> 11;
        const float* W = layer ? W2 : W1;
        const float* a = layer ? (sel ? ad2 : as2) : (sel ? ad1 : as1);
        const float* row = W + (size_t)d * 512 + hh * 128;
        const float* av = a + hh * 128;
        float s = 0.f;
        s += row[lane] * av[lane];
        s += row[lane + 64] * av[lane + 64];
#pragma unroll
        for (int off = 32; off; off >>= 1) s += __shfl_down(s, off);
        if (lane == 0) {
            _Float16* Wt = layer ? Wt2 : Wt1;
            Wt[(size_t)(512 + sel * 4 + hh) * 512 + d] = (_Float16)s;
        }
    } else if (w < 10240) {               // layer-3 projections: 2 sel x 2 h x 512 k
        int idx = w - 8192;
        int k = idx & 511, hh = (idx >> 9) & 1, sel = idx >> 10;
        const float* a = (sel ? ad3 : as3) + hh * 512;
        const float* row = W3 + (size_t)k * 1024 + hh * 512;
        float s = 0.f;
        for (int c = lane; c < 512; c += 64) s += row[c] * a[c];
#pragma unroll
        for (int off = 32; off; off >>= 1) s += __shfl_down(s, off);
        if (lane == 0) (sel ? wed3 : wes3)[hh * 512 + k] = s;
    } else if (w < 11136) {               // zero-fill Wt pad rows 520..575 (both layers)
        int z = (w - 10240) * 64 + lane;  // 0..57343
        int layer = z / 28672;
        int rem = z - layer * 28672;
        int row = 520 + rem / 512, col = rem & 511;
        (layer ? Wt2 : Wt1)[(size_t)row * 512 + col] = (_Float16)0.f;
    }
}

// ---------------- MFMA GEMM (layers 1/2: 64x64 tile) -----------------------

#define BK 64

__global__ __launch_bounds__(256) void gemm_f16_att(const _Float16* __restrict__ A,
                                                    const _Float16* __restrict__ Bt,
                                                    _Float16* __restrict__ Hout,
                                                    float* __restrict__ es,
                                                    float* __restrict__ ed,
                                                    int M, int K) {
    __shared__ _Float16 As[64 * BK];
    __shared__ _Float16 Bs[64 * BK];
    int tid = threadIdx.x;
    int lane = tid & 63, wave = tid >> 6;
    int wm = (wave & 1) * 32, wn = (wave >> 1) * 32;
    int m0 = blockIdx.y * 64, n0 = blockIdx.x * 64;
    int l15 = lane & 15, quad = lane >> 4;
    int trow = tid >> 3, tcol = tid & 7;

    floatx4 acc[2][2];
#pragma unroll
    for (int i = 0; i < 2; ++i)
#pragma unroll
        for (int j = 0; j < 2; ++j) acc[i][j] = (floatx4){0.f, 0.f, 0.f, 0.f};

    for (int k0 = 0; k0 < K; k0 += BK) {
        __syncthreads();
#pragma unroll
        for (int i = 0; i < 2; ++i) {
            int gr = m0 + i * 32 + trow; if (gr >= M) gr = M - 1;
            __builtin_amdgcn_global_load_lds(AS1(A + (size_t)gr * K + k0 + tcol * 8),
                                             AS3(As + (size_t)(i * 256 + tid) * 8), 16, 0, 0);
        }
#pragma unroll
        for (int i = 0; i < 2; ++i) {
            int gr = n0 + i * 32 + trow;
            __builtin_amdgcn_global_load_lds(AS1(Bt + (size_t)gr * K + k0 + tcol * 8),
                                             AS3(Bs + (size_t)(i * 256 + tid) * 8), 16, 0, 0);
        }
        __syncthreads();
#pragma unroll
        for (int ks = 0; ks < BK; ks += 32) {
            half8 af[2], bfr[2];
#pragma unroll
            for (int i = 0; i < 2; ++i)
                af[i] = *(const half8*)&As[(wm + i * 16 + l15) * BK + ks + quad * 8];
#pragma unroll
            for (int j = 0; j < 2; ++j)
                bfr[j] = *(const half8*)&Bs[(wn + j * 16 + l15) * BK + ks + quad * 8];
#pragma unroll
            for (int i = 0; i < 2; ++i)
#pragma unroll
                for (int j = 0; j < 2; ++j)
                    acc[i][j] = __builtin_amdgcn_mfma_f32_16x16x32_f16(af[i], bfr[j], acc[i][j], 0, 0, 0);
        }
    }
#pragma unroll
    for (int i = 0; i < 2; ++i)
#pragma unroll
        for (int j = 0; j < 2; ++j) {
            int col = n0 + wn + j * 16 + l15;
#pragma unroll
            for (int r = 0; r < 4; ++r) {
                int row = m0 + wm + i * 16 + quad * 4 + r;
                if (row < M) {
                    float v = acc[i][j][r];
                    if (col < 512) Hout[(size_t)row * 512 + col] = (_Float16)v;
                    else if (col < 516) es[row * 4 + col - 512] = v;
                    else if (col < 520) ed[row * 4 + col - 516] = v;
                }
            }
        }
}

// layer 3: 128x64 tile (acc 2x4 per wave), fp32 out, fused epilogue.
__global__ __launch_bounds__(256) void gemm_f16_ep(const _Float16* __restrict__ A,
                                                   const _Float16* __restrict__ Bt,
                                                   float* __restrict__ out,
                                                   const float* __restrict__ bias,
                                                   const _Float16* __restrict__ xres,
                                                   int M, int Nn, int K) {
    __shared__ _Float16 As[128 * BK];
    __shared__ _Float16 Bs[64 * BK];
    int tid = threadIdx.x;
    int lane = tid & 63, wave = tid >> 6;
    int wm = wave * 32;                     // 4 waves cover 128 rows
    int m0 = blockIdx.y * 128, n0 = blockIdx.x * 64;
    int l15 = lane & 15, quad = lane >> 4;
    int trow = tid >> 3, tcol = tid & 7;

    floatx4 acc[2][4];
#pragma unroll
    for (int i = 0; i < 2; ++i)
#pragma unroll
        for (int j = 0; j < 4; ++j) acc[i][j] = (floatx4){0.f, 0.f, 0.f, 0.f};

    for (int k0 = 0; k0 < K; k0 += BK) {
        __syncthreads();
#pragma unroll
        for (int i = 0; i < 4; ++i) {
            int gr = m0 + i * 32 + trow; if (gr >= M) gr = M - 1;
            __builtin_amdgcn_global_load_lds(AS1(A + (size_t)gr * K + k0 + tcol * 8),
                                             AS3(As + (size_t)(i * 256 + tid) * 8), 16, 0, 0);
        }
#pragma unroll
        for (int i = 0; i < 2; ++i) {
            int gr = n0 + i * 32 + trow;
            __builtin_amdgcn_global_load_lds(AS1(Bt + (size_t)gr * K + k0 + tcol * 8),
                                             AS3(Bs + (size_t)(i * 256 + tid) * 8), 16, 0, 0);
        }
        __syncthreads();
#pragma unroll
        for (int ks = 0; ks < BK; ks += 32) {
            half8 af[2], bfr[4];
#pragma unroll
            for (int i = 0; i < 2; ++i)
                af[i] = *(const half8*)&As[(wm + i * 16 + l15) * BK + ks + quad * 8];
#pragma unroll
            for (int j = 0; j < 4; ++j)
                bfr[j] = *(const half8*)&Bs[(j * 16 + l15) * BK + ks + quad * 8];
#pragma unroll
            for (int i = 0; i < 2; ++i)
#pragma unroll
                for (int j = 0; j < 4; ++j)
                    acc[i][j] = __builtin_amdgcn_mfma_f32_16x16x32_f16(af[i], bfr[j], acc[i][j], 0, 0, 0);
        }
    }
#pragma unroll
    for (int i = 0; i < 2; ++i)
#pragma unroll
        for (int j = 0; j < 4; ++j) {
            int col = n0 + j * 16 + l15;
#pragma unroll
            for (int r = 0; r < 4; ++r) {
                int row = m0 + wm + i * 16 + quad * 4 + r;
                if (row < M)
                    out[(size_t)row * Nn + col] =
                        0.5f * acc[i][j][r] + bias[col] + (float)xres[(size_t)row * Nn + col];
            }
        }
}

// ---------------- aggregation (layers 1/2): bulk-srcs independent gathers --

template <bool RES32, bool COEF3>
__global__ __launch_bounds__(512) void aggregate9_concat(
    const _Float16* __restrict__ h, const float* __restrict__ es,
    const float* __restrict__ ed,
    const int* __restrict__ row_start, const int* __restrict__ srcs,
    const float* __restrict__ bias, const float* __restrict__ xres32,
    const _Float16* __restrict__ xres16, _Float16* __restrict__ x_out_h,
    const float* __restrict__ wes3, const float* __restrict__ wed3,
    float* __restrict__ es3, float* __restrict__ ed3, int Nn) {
    int wave = threadIdx.x >> 6, lane = threadIdx.x & 63;
    int n = blockIdx.x * 8 + wave;
    if (n >= Nn) return;
    int head = lane >> 4;                 // C=128 -> 16 lanes per head
    int c0 = lane * 8;
    float edn = ed[n * 4 + head];
    int beg = row_start[n], end = row_start[n + 1];
    float acc[8] = {};
    float den = 0.f;
    int j = beg;
    // 16-edge groups: load all srcs first, then all es, then h in 8-batches.
    for (; j + 15 < end; j += 16) {
        int s[16];
#pragma unroll
        for (int q = 0; q < 16; ++q) s[q] = srcs[j + q];
        float e[16];
#pragma unroll
        for (int q = 0; q < 16; ++q) e[q] = es[s[q] * 4 + head];
#pragma unroll
        for (int hb = 0; hb < 2; ++hb) {
            half8 hv[8];
#pragma unroll
            for (int q = 0; q < 8; ++q)
                hv[q] = *(const half8*)&h[(size_t)s[hb * 8 + q] * 512 + c0];
#pragma unroll
            for (int q = 0; q < 8; ++q) {
                float w = leaky_exp(e[hb * 8 + q] + edn);
                den += w;
#pragma unroll
                for (int k = 0; k < 8; ++k) acc[k] += w * (float)hv[q][k];
            }
        }
    }
    for (; j + 7 < end; j += 8) {
        int s[8];
#pragma unroll
        for (int q = 0; q < 8; ++q) s[q] = srcs[j + q];
        float e[8];
#pragma unroll
        for (int q = 0; q < 8; ++q) e[q] = es[s[q] * 4 + head];
        half8 hv[8];
#pragma unroll
        for (int q = 0; q < 8; ++q) hv[q] = *(const half8*)&h[(size_t)s[q] * 512 + c0];
#pragma unroll
        for (int q = 0; q < 8; ++q) {
            float w = leaky_exp(e[q] + edn);
            den += w;
#pragma unroll
            for (int k = 0; k < 8; ++k) acc[k] += w * (float)hv[q][k];
        }
    }
    if (j < end) {
        int cnt = end - j;                // 1..7
        int s[7];
        float e[7];
        half8 hv[7];
#pragma unroll
        for (int q = 0; q < 7; ++q) s[q] = (q < cnt) ? srcs[j + q] : srcs[j];
#pragma unroll
        for (int q = 0; q < 7; ++q) e[q] = (q < cnt) ? es[s[q] * 4 + head] : 0.f;
#pragma unroll
        for (int q = 0; q < 7; ++q)
            hv[q] = *(const half8*)&h[(size_t)s[q] * 512 + c0];
#pragma unroll
        for (int q = 0; q < 7; ++q) {
            if (q < cnt) {
                float w = leaky_exp(e[q] + edn);
                den += w;
#pragma unroll
                for (int k = 0; k < 8; ++k) acc[k] += w * (float)hv[q][k];
            }
        }
    }
    float invden = 1.f / (den + 1e-16f);
    size_t base = (size_t)n * 512 + c0;
    float v[8];
    half8 o;
#pragma unroll
    for (int k = 0; k < 8; ++k) {
        float res = RES32 ? xres32[base + k] : (float)xres16[base + k];
        float t = acc[k] * invden + bias[c0 + k] + res;
        t = (t > 0.f) ? t : expm1f(t);
        v[k] = t;
        o[k] = (_Float16)t;
    }
    *(half8*)&x_out_h[base] = o;
    if (COEF3) {
        float t0 = 0.f, t1 = 0.f, t2 = 0.f, t3 = 0.f;
#pragma unroll
        for (int k = 0; k < 8; ++k) {
            t0 += v[k] * wes3[c0 + k];
            t1 += v[k] * wes3[512 + c0 + k];
            t2 += v[k] * wed3[c0 + k];
            t3 += v[k] * wed3[512 + c0 + k];
        }
#pragma unroll
        for (int off = 32; off; off >>= 1) {
            t0 += __shfl_down(t0, off);
            t1 += __shfl_down(t1, off);
            t2 += __shfl_down(t2, off);
            t3 += __shfl_down(t3, off);
        }
        if (lane == 0) {
            es3[n * 2] = t0; es3[n * 2 + 1] = t1;
            ed3[n * 2] = t2; ed3[n * 2 + 1] = t3;
        }
    }
}

// ---------------- aggregation (layer 3): bulk-srcs, dual heads -------------

__global__ __launch_bounds__(512) void aggregate9_dual(
    const _Float16* __restrict__ x, const float* __restrict__ es3,
    const float* __restrict__ ed3,
    const int* __restrict__ row_start, const int* __restrict__ srcs,
    _Float16* __restrict__ y, int Nn) {
    int wave = threadIdx.x >> 6, lane = threadIdx.x & 63;
    int n = blockIdx.x * 8 + wave;
    if (n >= Nn) return;
    int c0 = lane * 8;
    float edn0 = ed3[n * 2], edn1 = ed3[n * 2 + 1];
    int beg = row_start[n], end = row_start[n + 1];
    float a0[8] = {}, a1[8] = {};
    float den0 = 0.f, den1 = 0.f;
    int j = beg;
    for (; j + 15 < end; j += 16) {
        int s[16];
#pragma unroll
        for (int q = 0; q < 16; ++q) s[q] = srcs[j + q];
        float2 qq[16];
#pragma unroll
        for (int q = 0; q < 16; ++q) qq[q] = *(const float2*)&es3[s[q] * 2];
#pragma unroll
        for (int hb = 0; hb < 2; ++hb) {
            half8 hv[8];
#pragma unroll
            for (int q = 0; q < 8; ++q)
                hv[q] = *(const half8*)&x[(size_t)s[hb * 8 + q] * 512 + c0];
#pragma unroll
            for (int q = 0; q < 8; ++q) {
                float u = leaky_exp(qq[hb * 8 + q].x + edn0);
                float v = leaky_exp(qq[hb * 8 + q].y + edn1);
                den0 += u; den1 += v;
#pragma unroll
                for (int k = 0; k < 8; ++k) { float f = (float)hv[q][k]; a0[k] += u * f; a1[k] += v * f; }
            }
        }
    }
    for (; j + 7 < end; j += 8) {
        int s[8];
#pragma unroll
        for (int q = 0; q < 8; ++q) s[q] = srcs[j + q];
        float2 qq[8];
#pragma unroll
        for (int q = 0; q < 8; ++q) qq[q] = *(const float2*)&es3[s[q] * 2];
        half8 hv[8];
#pragma unroll
        for (int q = 0; q < 8; ++q) hv[q] = *(const half8*)&x[(size_t)s[q] * 512 + c0];
#pragma unroll
        for (int q = 0; q < 8; ++q) {
            float u = leaky_exp(qq[q].x + edn0);
            float v = leaky_exp(qq[q].y + edn1);
            den0 += u; den1 += v;
#pragma unroll
            for (int k = 0; k < 8; ++k) { float f = (float)hv[q][k]; a0[k] += u * f; a1[k] += v * f; }
        }
    }
    if (j < end) {
        int cnt = end - j;
        int s[7];
        float2 qq[7];
        half8 hv[7];
#pragma unroll
        for (int q = 0; q < 7; ++q) s[q] = (q < cnt) ? srcs[j + q] : srcs[j];
#pragma unroll
        for (int q = 0; q < 7; ++q) qq[q] = *(const float2*)&es3[s[q] * 2];
#pragma unroll
        for (int q = 0; q < 7; ++q) hv[q] = *(const half8*)&x[(size_t)s[q] * 512 + c0];
#pragma unroll
        for (int q = 0; q < 7; ++q) {
            if (q < cnt) {
                float u = leaky_exp(qq[q].x + edn0);
                float v = leaky_exp(qq[q].y + edn1);
                den0 += u; den1 += v;
#pragma unroll
                for (int k = 0; k < 8; ++k) { float f = (float)hv[q][k]; a0[k] += u * f; a1[k] += v * f; }
            }
        }
    }
    float invd0 = 1.f / (den0 + 1e-16f);
    float invd1 = 1.f / (den1 + 1e-16f);
    half8 o0, o1;
#pragma unroll
    for (int k = 0; k < 8; ++k) {
        o0[k] = (_Float16)(a0[k] * invd0);
        o1[k] = (_Float16)(a1[k] * invd1);
    }
    *(half8*)&y[(size_t)n * 1024 + c0] = o0;
    *(half8*)&y[(size_t)n * 1024 + 512 + c0] = o1;
}

// ---------------------------------------------------------------------------

extern "C" void kernel_launch(void* const* d_in, const int* in_sizes, int n_in,
                              void* d_out, int out_size, void* d_ws, size_t ws_size,
                              hipStream_t stream) {
    const float* graph = (const float*)d_in[0];
    const int* edge_index = (const int*)d_in[1];
    const float* W1 = (const float*)d_in[2];
    const float* as1 = (const float*)d_in[3];
    const float* ad1 = (const float*)d_in[4];
    const float* b1 = (const float*)d_in[5];
    const float* W2 = (const float*)d_in[6];
    const float* as2 = (const float*)d_in[7];
    const float* ad2 = (const float*)d_in[8];
    const float* b2 = (const float*)d_in[9];
    const float* W3 = (const float*)d_in[10];
    const float* as3 = (const float*)d_in[11];
    const float* ad3 = (const float*)d_in[12];
    const float* b3 = (const float*)d_in[13];

    const int D = 512;
    int N = in_sizes[0] / D;       // 10000
    int E = in_sizes[1] / 2;       // 160000
    const int* src = edge_index;
    const int* dst = edge_index + E;

    char* p = (char*)d_ws;
    auto carve = [&](size_t bytes) {
        void* r = (void*)p;
        p += (bytes + 255) & ~(size_t)255;
        return r;
    };
    _Float16* Ah   = (_Float16*)carve((size_t)N * 512 * 2);    // x (f16), rewritten per layer
    _Float16* Wt1  = (_Float16*)carve((size_t)576 * 512 * 2);  // W1^T + attn rows + pad
    _Float16* Wt2  = (_Float16*)carve((size_t)576 * 512 * 2);
    _Float16* Bt3  = (_Float16*)carve((size_t)512 * 1024 * 2); // layer-3 stacked B^T
    _Float16* h_h  = (_Float16*)carve((size_t)N * 1024 * 2);   // h (l1/2, ld 512) / y (l3, ld 1024)
    float* es      = (float*)carve((size_t)N * 4 * 4);
    float* ed      = (float*)carve((size_t)N * 4 * 4);
    float* es3     = (float*)carve((size_t)N * 2 * 4);
    float* ed3     = (float*)carve((size_t)N * 2 * 4);
    float* wes3    = (float*)carve((size_t)2 * 512 * 4);
    float* wed3    = (float*)carve((size_t)2 * 512 * 4);
    int* deg       = (int*)carve((size_t)N * 4);
    int* cur       = (int*)carve((size_t)N * 4);
    int* row_st    = (int*)carve((size_t)(N + 1) * 4);
    int* srcs      = (int*)carve((size_t)E * 4);

    // ---- CSR by dst (shared by all layers) ----
    hipMemsetAsync(deg, 0, (size_t)N * 4, stream);
    count_deg<<<(E + 255) / 256, 256, 0, stream>>>(dst, deg, E);
    scan_kernel<<<1, 1024, 0, stream>>>(deg, row_st, cur, N);
    scatter_edges<<<(E + 255) / 256, 256, 0, stream>>>(src, dst, cur, srcs, E);

    // ---- prep (single kernel): cast + transposes + projections ----
    int n4 = N * 512 / 4;
    int cb = (n4 + 255) / 256;
    prep_all<<<cb + 1024 + 2784, 256, 0, stream>>>(
        graph, Ah, n4, cb, W1, W2, W3, Wt1, Wt2, Bt3,
        as1, ad1, as2, ad2, as3, ad3, wes3, wed3);

    int nblk8 = (N + 7) / 8;
    int mblk = (N + 63) / 64;
    int mblk128 = (N + 127) / 128;
    // ---- Layer 1 ----
    gemm_f16_att<<<dim3(9, mblk), 256, 0, stream>>>(Ah, Wt1, h_h, es, ed, N, 512);
    aggregate9_concat<true, false><<<nblk8, 512, 0, stream>>>(
        h_h, es, ed, row_st, srcs, b1, graph, nullptr, Ah,
        nullptr, nullptr, nullptr, nullptr, N);

    // ---- Layer 2 (also emits layer-3 es3/ed3 in epilogue) ----
    gemm_f16_att<<<dim3(9, mblk), 256, 0, stream>>>(Ah, Wt2, h_h, es, ed, N, 512);
    aggregate9_concat<false, true><<<nblk8, 512, 0, stream>>>(
        h_h, es, ed, row_st, srcs, b2, nullptr, Ah, Ah,
        wes3, wed3, es3, ed3, N);

    // ---- Layer 3: aggregate-then-transform ----
    aggregate9_dual<<<nblk8, 512, 0, stream>>>(Ah, es3, ed3, row_st, srcs, h_h, N);
    gemm_f16_ep<<<dim3(8, mblk128), 256, 0, stream>>>(
        h_h, Bt3, (float*)d_out, b3, Ah, N, 512, 1024);
}

// Round 12
// 311.148 us; speedup vs baseline: 1.0861x; 1.0861x over previous
//
#include <hip/hip_runtime.h>
#include <hip/hip_bf16.h>
#include <hip/hip_fp16.h>
#include <cstddef>
#include <cstdint>

// ---------------------------------------------------------------------------
// GAT 3-layer network. R12: revert aggregates to R9 4-deep form (R11's bulk-16
// collapsed occupancy 46->17%), thread-local-16 single-pass scan (~12us -> ~2us),
// count_deg folded into prep_all.
// ---------------------------------------------------------------------------

typedef _Float16 half8 __attribute__((ext_vector_type(8)));
typedef _Float16 half4v __attribute__((ext_vector_type(4)));
typedef float floatx4 __attribute__((ext_vector_type(4)));

#define AS1(p) ((const __attribute__((address_space(1))) void*)(p))
#define AS3(p) ((__attribute__((address_space(3))) void*)(p))

__device__ __forceinline__ float leaky_exp(float e) {
    e = (e > 0.f) ? e : 0.2f * e;
    return __expf(e);
}

// ---------------- CSR: fast single-pass scan ----------------
// 1024 threads; thread t locally scans deg[t*16 .. t*16+15] in registers,
// then block-scan of thread sums. One outer iter for n<=16384.

__global__ void scan_kernel(const int* __restrict__ deg, int* __restrict__ row_start,
                            int* __restrict__ cursor, int n) {
    __shared__ int wsum[16];
    __shared__ int carry_s;
    int tid = threadIdx.x;              // 1024
    int wave = tid >> 6, lane = tid & 63;
    if (tid == 0) { carry_s = 0; row_start[0] = 0; }
    __syncthreads();
    const int CH = 16;
    for (int base = 0; base < n; base += 1024 * CH) {
        int i0 = base + tid * CH;
        int loc[CH];
        int tsum = 0;
#pragma unroll
        for (int q = 0; q < CH; ++q) {
            int idx = i0 + q;
            int v = (idx < n) ? deg[idx] : 0;
            tsum += v;
            loc[q] = tsum;              // inclusive within thread
        }
        int x = tsum;
#pragma unroll
        for (int off = 1; off < 64; off <<= 1) {
            int t = __shfl_up(x, off);
            if (lane >= off) x += t;
        }
        if (lane == 63) wsum[wave] = x;
        __syncthreads();
        if (wave == 0 && lane < 16) {
            int w = wsum[lane];
#pragma unroll
            for (int off = 1; off < 16; off <<= 1) {
                int t = __shfl_up(w, off);
                if (lane >= off) w += t;
            }
            wsum[lane] = w;
        }
        __syncthreads();
        int carry = carry_s;
        int toff = carry + (wave ? wsum[wave - 1] : 0) + (x - tsum);  // excl prefix of thread
#pragma unroll
        for (int q = 0; q < CH; ++q) {
            int idx = i0 + q;
            if (idx < n) {
                int excl = toff + (q ? loc[q - 1] : 0);
                row_start[idx + 1] = toff + loc[q];
                cursor[idx] = excl;
            }
        }
        __syncthreads();
        if (tid == 0) carry_s = carry + wsum[15];
        __syncthreads();
    }
}

__global__ void scatter_edges(const int* __restrict__ src, const int* __restrict__ dst,
                              int* __restrict__ cursor, int* __restrict__ srcs, int E) {
    int e = blockIdx.x * blockDim.x + threadIdx.x;
    if (e < E) {
        int p = atomicAdd(&cursor[dst[e]], 1);
        srcs[p] = src[e];
    }
}

// ---------------- merged prep: cast + transposes + projections + count_deg --
// block ranges: [0,cb) cast; [cb,cb+1024) transpose; [cb+1024,pb) projections;
// [pb, pb+eb) count_deg.

__global__ void prep_all(const float* __restrict__ graph, _Float16* __restrict__ Ah, int n4,
                         int cb, int pb,
                         const float* __restrict__ W1, const float* __restrict__ W2,
                         const float* __restrict__ W3,
                         _Float16* __restrict__ Wt1, _Float16* __restrict__ Wt2,
                         _Float16* __restrict__ Bt3,
                         const float* __restrict__ as1, const float* __restrict__ ad1,
                         const float* __restrict__ as2, const float* __restrict__ ad2,
                         const float* __restrict__ as3, const float* __restrict__ ad3,
                         float* __restrict__ wes3, float* __restrict__ wed3,
                         const int* __restrict__ dst, int* __restrict__ deg, int E) {
    int b = blockIdx.x;
    int tid = threadIdx.x;              // 256
    if (b < cb) {                       // ---- cast graph -> f16 ----
        int i = b * 256 + tid;
        if (i < n4) {
            float4 v = ((const float4*)graph)[i];
            half4v o = {(_Float16)v.x, (_Float16)v.y, (_Float16)v.z, (_Float16)v.w};
            ((half4v*)Ah)[i] = o;
        }
        return;
    }
    if (b < cb + 1024) {                // ---- transpose-cast weights ----
        __shared__ float t[32][33];
        int bb = b - cb;
        int region = bb >> 8, idx = bb & 255;
        int r0 = (idx >> 4) * 32, c0 = (idx & 15) * 32;
        const float* in;
        _Float16* out;
        int in_ld, out_ld;
        if (region == 0)      { in = W1;       out = Wt1;       in_ld = 512;  out_ld = 512;  }
        else if (region == 1) { in = W2;       out = Wt2;       in_ld = 512;  out_ld = 512;  }
        else if (region == 2) { in = W3;       out = Bt3;       in_ld = 1024; out_ld = 1024; }
        else                  { in = W3 + 512; out = Bt3 + 512; in_ld = 1024; out_ld = 1024; }
        int tx = tid & 31, ty = tid >> 5;   // 32 x 8
        for (int i = ty; i < 32; i += 8)
            t[i][tx] = in[(size_t)(r0 + i) * in_ld + c0 + tx];
        __syncthreads();
        for (int i = ty; i < 32; i += 8)
            out[(size_t)(c0 + i) * out_ld + r0 + tx] = (_Float16)t[tx][i];
        return;
    }
    if (b >= pb) {                      // ---- count_deg ----
        int e = (b - pb) * 256 + tid;
        if (e < E) atomicAdd(&deg[dst[e]], 1);
        return;
    }
    // ---- attention projections ----
    int w = (b - cb - 1024) * 4 + (tid >> 6);
    int lane = tid & 63;
    if (w < 8192) {                       // Wt1/Wt2 attn rows: 2 layers x 2 sel x 4 h x 512 d
        int layer = w >> 12;
        int idx = w & 4095;
        int d = idx & 511, hh = (idx >> 9) & 3, sel = idx >> 11;
        const float* W = layer ? W2 : W1;
        const float* a = layer ? (sel ? ad2 : as2) : (sel ? ad1 : as1);
        const float* row = W + (size_t)d * 512 + hh * 128;
        const float* av = a + hh * 128;
        float s = 0.f;
        s += row[lane] * av[lane];
        s += row[lane + 64] * av[lane + 64];
#pragma unroll
        for (int off = 32; off; off >>= 1) s += __shfl_down(s, off);
        if (lane == 0) {
            _Float16* Wt = layer ? Wt2 : Wt1;
            Wt[(size_t)(512 + sel * 4 + hh) * 512 + d] = (_Float16)s;
        }
    } else if (w < 10240) {               // layer-3 projections: 2 sel x 2 h x 512 k
        int idx = w - 8192;
        int k = idx & 511, hh = (idx >> 9) & 1, sel = idx >> 10;
        const float* a = (sel ? ad3 : as3) + hh * 512;
        const float* row = W3 + (size_t)k * 1024 + hh * 512;
        float s = 0.f;
        for (int c = lane; c < 512; c += 64) s += row[c] * a[c];
#pragma unroll
        for (int off = 32; off; off >>= 1) s += __shfl_down(s, off);
        if (lane == 0) (sel ? wed3 : wes3)[hh * 512 + k] = s;
    } else if (w < 11136) {               // zero-fill Wt pad rows 520..575 (both layers)
        int z = (w - 10240) * 64 + lane;  // 0..57343
        int layer = z / 28672;
        int rem = z - layer * 28672;
        int row = 520 + rem / 512, col = rem & 511;
        (layer ? Wt2 : Wt1)[(size_t)row * 512 + col] = (_Float16)0.f;
    }
}

// ---------------- MFMA GEMM (layers 1/2: 64x64 tile) -----------------------

#define BK 64

__global__ __launch_bounds__(256) void gemm_f16_att(const _Float16* __restrict__ A,
                                                    const _Float16* __restrict__ Bt,
                                                    _Float16* __restrict__ Hout,
                                                    float* __restrict__ es,
                                                    float* __restrict__ ed,
                                                    int M, int K) {
    __shared__ _Float16 As[64 * BK];
    __shared__ _Float16 Bs[64 * BK];
    int tid = threadIdx.x;
    int lane = tid & 63, wave = tid >> 6;
    int wm = (wave & 1) * 32, wn = (wave >> 1) * 32;
    int m0 = blockIdx.y * 64, n0 = blockIdx.x * 64;
    int l15 = lane & 15, quad = lane >> 4;
    int trow = tid >> 3, tcol = tid & 7;

    floatx4 acc[2][2];
#pragma unroll
    for (int i = 0; i < 2; ++i)
#pragma unroll
        for (int j = 0; j < 2; ++j) acc[i][j] = (floatx4){0.f, 0.f, 0.f, 0.f};

    for (int k0 = 0; k0 < K; k0 += BK) {
        __syncthreads();
#pragma unroll
        for (int i = 0; i < 2; ++i) {
            int gr = m0 + i * 32 + trow; if (gr >= M) gr = M - 1;
            __builtin_amdgcn_global_load_lds(AS1(A + (size_t)gr * K + k0 + tcol * 8),
                                             AS3(As + (size_t)(i * 256 + tid) * 8), 16, 0, 0);
        }
#pragma unroll
        for (int i = 0; i < 2; ++i) {
            int gr = n0 + i * 32 + trow;
            __builtin_amdgcn_global_load_lds(AS1(Bt + (size_t)gr * K + k0 + tcol * 8),
                                             AS3(Bs + (size_t)(i * 256 + tid) * 8), 16, 0, 0);
        }
        __syncthreads();
#pragma unroll
        for (int ks = 0; ks < BK; ks += 32) {
            half8 af[2], bfr[2];
#pragma unroll
            for (int i = 0; i < 2; ++i)
                af[i] = *(const half8*)&As[(wm + i * 16 + l15) * BK + ks + quad * 8];
#pragma unroll
            for (int j = 0; j < 2; ++j)
                bfr[j] = *(const half8*)&Bs[(wn + j * 16 + l15) * BK + ks + quad * 8];
#pragma unroll
            for (int i = 0; i < 2; ++i)
#pragma unroll
                for (int j = 0; j < 2; ++j)
                    acc[i][j] = __builtin_amdgcn_mfma_f32_16x16x32_f16(af[i], bfr[j], acc[i][j], 0, 0, 0);
        }
    }
#pragma unroll
    for (int i = 0; i < 2; ++i)
#pragma unroll
        for (int j = 0; j < 2; ++j) {
            int col = n0 + wn + j * 16 + l15;
#pragma unroll
            for (int r = 0; r < 4; ++r) {
                int row = m0 + wm + i * 16 + quad * 4 + r;
                if (row < M) {
                    float v = acc[i][j][r];
                    if (col < 512) Hout[(size_t)row * 512 + col] = (_Float16)v;
                    else if (col < 516) es[row * 4 + col - 512] = v;
                    else if (col < 520) ed[row * 4 + col - 516] = v;
                }
            }
        }
}

// layer 3: 128x64 tile (acc 2x4 per wave), fp32 out, fused epilogue.
__global__ __launch_bounds__(256) void gemm_f16_ep(const _Float16* __restrict__ A,
                                                   const _Float16* __restrict__ Bt,
                                                   float* __restrict__ out,
                                                   const float* __restrict__ bias,
                                                   const _Float16* __restrict__ xres,
                                                   int M, int Nn, int K) {
    __shared__ _Float16 As[128 * BK];
    __shared__ _Float16 Bs[64 * BK];
    int tid = threadIdx.x;
    int lane = tid & 63, wave = tid >> 6;
    int wm = wave * 32;                     // 4 waves cover 128 rows
    int m0 = blockIdx.y * 128, n0 = blockIdx.x * 64;
    int l15 = lane & 15, quad = lane >> 4;
    int trow = tid >> 3, tcol = tid & 7;

    floatx4 acc[2][4];
#pragma unroll
    for (int i = 0; i < 2; ++i)
#pragma unroll
        for (int j = 0; j < 4; ++j) acc[i][j] = (floatx4){0.f, 0.f, 0.f, 0.f};

    for (int k0 = 0; k0 < K; k0 += BK) {
        __syncthreads();
#pragma unroll
        for (int i = 0; i < 4; ++i) {
            int gr = m0 + i * 32 + trow; if (gr >= M) gr = M - 1;
            __builtin_amdgcn_global_load_lds(AS1(A + (size_t)gr * K + k0 + tcol * 8),
                                             AS3(As + (size_t)(i * 256 + tid) * 8), 16, 0, 0);
        }
#pragma unroll
        for (int i = 0; i < 2; ++i) {
            int gr = n0 + i * 32 + trow;
            __builtin_amdgcn_global_load_lds(AS1(Bt + (size_t)gr * K + k0 + tcol * 8),
                                             AS3(Bs + (size_t)(i * 256 + tid) * 8), 16, 0, 0);
        }
        __syncthreads();
#pragma unroll
        for (int ks = 0; ks < BK; ks += 32) {
            half8 af[2], bfr[4];
#pragma unroll
            for (int i = 0; i < 2; ++i)
                af[i] = *(const half8*)&As[(wm + i * 16 + l15) * BK + ks + quad * 8];
#pragma unroll
            for (int j = 0; j < 4; ++j)
                bfr[j] = *(const half8*)&Bs[(j * 16 + l15) * BK + ks + quad * 8];
#pragma unroll
            for (int i = 0; i < 2; ++i)
#pragma unroll
                for (int j = 0; j < 4; ++j)
                    acc[i][j] = __builtin_amdgcn_mfma_f32_16x16x32_f16(af[i], bfr[j], acc[i][j], 0, 0, 0);
        }
    }
#pragma unroll
    for (int i = 0; i < 2; ++i)
#pragma unroll
        for (int j = 0; j < 4; ++j) {
            int col = n0 + j * 16 + l15;
#pragma unroll
            for (int r = 0; r < 4; ++r) {
                int row = m0 + wm + i * 16 + quad * 4 + r;
                if (row < M)
                    out[(size_t)row * Nn + col] =
                        0.5f * acc[i][j][r] + bias[col] + (float)xres[(size_t)row * Nn + col];
            }
        }
}

// ---------------- aggregation (layers 1/2): fused softmax, 4-deep (R9) -----

template <bool RES32, bool COEF3>
__global__ __launch_bounds__(512) void aggregate7_concat(
    const _Float16* __restrict__ h, const float* __restrict__ es,
    const float* __restrict__ ed,
    const int* __restrict__ row_start, const int* __restrict__ srcs,
    const float* __restrict__ bias, const float* __restrict__ xres32,
    const _Float16* __restrict__ xres16, _Float16* __restrict__ x_out_h,
    const float* __restrict__ wes3, const float* __restrict__ wed3,
    float* __restrict__ es3, float* __restrict__ ed3, int Nn) {
    int wave = threadIdx.x >> 6, lane = threadIdx.x & 63;
    int n = blockIdx.x * 8 + wave;
    if (n >= Nn) return;
    int head = lane >> 4;                 // C=128 -> 16 lanes per head
    int c0 = lane * 8;
    float edn = ed[n * 4 + head];
    int beg = row_start[n], end = row_start[n + 1];
    float acc[8] = {};
    float den = 0.f;
    int j = beg;
    for (; j + 3 < end; j += 4) {
        int s0 = srcs[j], s1 = srcs[j + 1], s2 = srcs[j + 2], s3 = srcs[j + 3];
        float e0 = es[s0 * 4 + head], e1 = es[s1 * 4 + head];
        float e2 = es[s2 * 4 + head], e3 = es[s3 * 4 + head];
        half8 h0 = *(const half8*)&h[(size_t)s0 * 512 + c0];
        half8 h1 = *(const half8*)&h[(size_t)s1 * 512 + c0];
        half8 h2 = *(const half8*)&h[(size_t)s2 * 512 + c0];
        half8 h3 = *(const half8*)&h[(size_t)s3 * 512 + c0];
        float w0 = leaky_exp(e0 + edn), w1 = leaky_exp(e1 + edn);
        float w2 = leaky_exp(e2 + edn), w3 = leaky_exp(e3 + edn);
        den += w0 + w1 + w2 + w3;
#pragma unroll
        for (int k = 0; k < 8; ++k) acc[k] += w0 * (float)h0[k];
#pragma unroll
        for (int k = 0; k < 8; ++k) acc[k] += w1 * (float)h1[k];
#pragma unroll
        for (int k = 0; k < 8; ++k) acc[k] += w2 * (float)h2[k];
#pragma unroll
        for (int k = 0; k < 8; ++k) acc[k] += w3 * (float)h3[k];
    }
    for (; j < end; ++j) {
        int s = srcs[j];
        float w = leaky_exp(es[s * 4 + head] + edn);
        half8 hv = *(const half8*)&h[(size_t)s * 512 + c0];
        den += w;
#pragma unroll
        for (int k = 0; k < 8; ++k) acc[k] += w * (float)hv[k];
    }
    float invden = 1.f / (den + 1e-16f);
    size_t base = (size_t)n * 512 + c0;
    float v[8];
    half8 o;
#pragma unroll
    for (int k = 0; k < 8; ++k) {
        float res = RES32 ? xres32[base + k] : (float)xres16[base + k];
        float t = acc[k] * invden + bias[c0 + k] + res;
        t = (t > 0.f) ? t : expm1f(t);
        v[k] = t;
        o[k] = (_Float16)t;
    }
    *(half8*)&x_out_h[base] = o;
    if (COEF3) {
        float t0 = 0.f, t1 = 0.f, t2 = 0.f, t3 = 0.f;
#pragma unroll
        for (int k = 0; k < 8; ++k) {
            t0 += v[k] * wes3[c0 + k];
            t1 += v[k] * wes3[512 + c0 + k];
            t2 += v[k] * wed3[c0 + k];
            t3 += v[k] * wed3[512 + c0 + k];
        }
#pragma unroll
        for (int off = 32; off; off >>= 1) {
            t0 += __shfl_down(t0, off);
            t1 += __shfl_down(t1, off);
            t2 += __shfl_down(t2, off);
            t3 += __shfl_down(t3, off);
        }
        if (lane == 0) {
            es3[n * 2] = t0; es3[n * 2 + 1] = t1;
            ed3[n * 2] = t2; ed3[n * 2 + 1] = t3;
        }
    }
}

// ---------------- aggregation (layer 3): fused softmax, dual heads, 4-deep --

__global__ __launch_bounds__(512) void aggregate7_dual(
    const _Float16* __restrict__ x, const float* __restrict__ es3,
    const float* __restrict__ ed3,
    const int* __restrict__ row_start, const int* __restrict__ srcs,
    _Float16* __restrict__ y, int Nn) {
    int wave = threadIdx.x >> 6, lane = threadIdx.x & 63;
    int n = blockIdx.x * 8 + wave;
    if (n >= Nn) return;
    int c0 = lane * 8;
    float edn0 = ed3[n * 2], edn1 = ed3[n * 2 + 1];
    int beg = row_start[n], end = row_start[n + 1];
    float a0[8] = {}, a1[8] = {};
    float den0 = 0.f, den1 = 0.f;
    int j = beg;
    for (; j + 3 < end; j += 4) {
        int s0 = srcs[j], s1 = srcs[j + 1], s2 = srcs[j + 2], s3 = srcs[j + 3];
        float2 q0 = *(const float2*)&es3[s0 * 2];
        float2 q1 = *(const float2*)&es3[s1 * 2];
        float2 q2 = *(const float2*)&es3[s2 * 2];
        float2 q3 = *(const float2*)&es3[s3 * 2];
        half8 h0 = *(const half8*)&x[(size_t)s0 * 512 + c0];
        half8 h1 = *(const half8*)&x[(size_t)s1 * 512 + c0];
        half8 h2 = *(const half8*)&x[(size_t)s2 * 512 + c0];
        half8 h3 = *(const half8*)&x[(size_t)s3 * 512 + c0];
        float u0 = leaky_exp(q0.x + edn0), v0 = leaky_exp(q0.y + edn1);
        float u1 = leaky_exp(q1.x + edn0), v1 = leaky_exp(q1.y + edn1);
        float u2 = leaky_exp(q2.x + edn0), v2 = leaky_exp(q2.y + edn1);
        float u3 = leaky_exp(q3.x + edn0), v3 = leaky_exp(q3.y + edn1);
        den0 += u0 + u1 + u2 + u3;
        den1 += v0 + v1 + v2 + v3;
#pragma unroll
        for (int k = 0; k < 8; ++k) { float f = (float)h0[k]; a0[k] += u0 * f; a1[k] += v0 * f; }
#pragma unroll
        for (int k = 0; k < 8; ++k) { float f = (float)h1[k]; a0[k] += u1 * f; a1[k] += v1 * f; }
#pragma unroll
        for (int k = 0; k < 8; ++k) { float f = (float)h2[k]; a0[k] += u2 * f; a1[k] += v2 * f; }
#pragma unroll
        for (int k = 0; k < 8; ++k) { float f = (float)h3[k]; a0[k] += u3 * f; a1[k] += v3 * f; }
    }
    for (; j < end; ++j) {
        int s = srcs[j];
        float2 q = *(const float2*)&es3[s * 2];
        float u = leaky_exp(q.x + edn0), v = leaky_exp(q.y + edn1);
        half8 hv = *(const half8*)&x[(size_t)s * 512 + c0];
        den0 += u; den1 += v;
#pragma unroll
        for (int k = 0; k < 8; ++k) { float f = (float)hv[k]; a0[k] += u * f; a1[k] += v * f; }
    }
    float invd0 = 1.f / (den0 + 1e-16f);
    float invd1 = 1.f / (den1 + 1e-16f);
    half8 o0, o1;
#pragma unroll
    for (int k = 0; k < 8; ++k) {
        o0[k] = (_Float16)(a0[k] * invd0);
        o1[k] = (_Float16)(a1[k] * invd1);
    }
    *(half8*)&y[(size_t)n * 1024 + c0] = o0;
    *(half8*)&y[(size_t)n * 1024 + 512 + c0] = o1;
}

// ---------------------------------------------------------------------------

extern "C" void kernel_launch(void* const* d_in, const int* in_sizes, int n_in,
                              void* d_out, int out_size, void* d_ws, size_t ws_size,
                              hipStream_t stream) {
    const float* graph = (const float*)d_in[0];
    const int* edge_index = (const int*)d_in[1];
    const float* W1 = (const float*)d_in[2];
    const float* as1 = (const float*)d_in[3];
    const float* ad1 = (const float*)d_in[4];
    const float* b1 = (const float*)d_in[5];
    const float* W2 = (const float*)d_in[6];
    const float* as2 = (const float*)d_in[7];
    const float* ad2 = (const float*)d_in[8];
    const float* b2 = (const float*)d_in[9];
    const float* W3 = (const float*)d_in[10];
    const float* as3 = (const float*)d_in[11];
    const float* ad3 = (const float*)d_in[12];
    const float* b3 = (const float*)d_in[13];

    const int D = 512;
    int N = in_sizes[0] / D;       // 10000
    int E = in_sizes[1] / 2;       // 160000
    const int* src = edge_index;
    const int* dst = edge_index + E;

    char* p = (char*)d_ws;
    auto carve = [&](size_t bytes) {
        void* r = (void*)p;
        p += (bytes + 255) & ~(size_t)255;
        return r;
    };
    _Float16* Ah   = (_Float16*)carve((size_t)N * 512 * 2);    // x (f16), rewritten per layer
    _Float16* Wt1  = (_Float16*)carve((size_t)576 * 512 * 2);  // W1^T + attn rows + pad
    _Float16* Wt2  = (_Float16*)carve((size_t)576 * 512 * 2);
    _Float16* Bt3  = (_Float16*)carve((size_t)512 * 1024 * 2); // layer-3 stacked B^T
    _Float16* h_h  = (_Float16*)carve((size_t)N * 1024 * 2);   // h (l1/2, ld 512) / y (l3, ld 1024)
    float* es      = (float*)carve((size_t)N * 4 * 4);
    float* ed      = (float*)carve((size_t)N * 4 * 4);
    float* es3     = (float*)carve((size_t)N * 2 * 4);
    float* ed3     = (float*)carve((size_t)N * 2 * 4);
    float* wes3    = (float*)carve((size_t)2 * 512 * 4);
    float* wed3    = (float*)carve((size_t)2 * 512 * 4);
    int* deg       = (int*)carve((size_t)N * 4);
    int* cur       = (int*)carve((size_t)N * 4);
    int* row_st    = (int*)carve((size_t)(N + 1) * 4);
    int* srcs      = (int*)carve((size_t)E * 4);

    // ---- prep (single kernel): cast + transposes + projections + count_deg -
    hipMemsetAsync(deg, 0, (size_t)N * 4, stream);
    int n4 = N * 512 / 4;
    int cb = (n4 + 255) / 256;
    int pb = cb + 1024 + 2784;
    int eb = (E + 255) / 256;
    prep_all<<<pb + eb, 256, 0, stream>>>(
        graph, Ah, n4, cb, pb, W1, W2, W3, Wt1, Wt2, Bt3,
        as1, ad1, as2, ad2, as3, ad3, wes3, wed3, dst, deg, E);

    // ---- CSR (shared by all layers) ----
    scan_kernel<<<1, 1024, 0, stream>>>(deg, row_st, cur, N);
    scatter_edges<<<(E + 255) / 256, 256, 0, stream>>>(src, dst, cur, srcs, E);

    int nblk8 = (N + 7) / 8;
    int mblk = (N + 63) / 64;
    int mblk128 = (N + 127) / 128;
    // ---- Layer 1 ----
    gemm_f16_att<<<dim3(9, mblk), 256, 0, stream>>>(Ah, Wt1, h_h, es, ed, N, 512);
    aggregate7_concat<true, false><<<nblk8, 512, 0, stream>>>(
        h_h, es, ed, row_st, srcs, b1, graph, nullptr, Ah,
        nullptr, nullptr, nullptr, nullptr, N);

    // ---- Layer 2 (also emits layer-3 es3/ed3 in epilogue) ----
    gemm_f16_att<<<dim3(9, mblk), 256, 0, stream>>>(Ah, Wt2, h_h, es, ed, N, 512);
    aggregate7_concat<false, true><<<nblk8, 512, 0, stream>>>(
        h_h, es, ed, row_st, srcs, b2, nullptr, Ah, Ah,
        wes3, wed3, es3, ed3, N);

    // ---- Layer 3: aggregate-then-transform ----
    aggregate7_dual<<<nblk8, 512, 0, stream>>>(Ah, es3, ed3, row_st, srcs, h_h, N);
    gemm_f16_ep<<<dim3(8, mblk128), 256, 0, stream>>>(
        h_h, Bt3, (float*)d_out, b3, Ah, N, 512, 1024);
}

// Round 13
// 303.466 us; speedup vs baseline: 1.1136x; 1.0253x over previous
//
#include <hip/hip_runtime.h>
#include <hip/hip_bf16.h>
#include <hip/hip_fp16.h>
#include <cstddef>
#include <cstdint>

// ---------------------------------------------------------------------------
// GAT 3-layer network. R13: aggregation split 2 waves/node (even/odd edges,
// 4-deep pipeline each, 2-way LDS combine) — doubles wave-level parallelism
// without the R11 VGPR blowup. Everything else = R12.
// ---------------------------------------------------------------------------

typedef _Float16 half8 __attribute__((ext_vector_type(8)));
typedef _Float16 half4v __attribute__((ext_vector_type(4)));
typedef float floatx4 __attribute__((ext_vector_type(4)));

#define AS1(p) ((const __attribute__((address_space(1))) void*)(p))
#define AS3(p) ((__attribute__((address_space(3))) void*)(p))

__device__ __forceinline__ float leaky_exp(float e) {
    e = (e > 0.f) ? e : 0.2f * e;
    return __expf(e);
}

// ---------------- CSR: fast single-pass scan ----------------

__global__ void scan_kernel(const int* __restrict__ deg, int* __restrict__ row_start,
                            int* __restrict__ cursor, int n) {
    __shared__ int wsum[16];
    __shared__ int carry_s;
    int tid = threadIdx.x;              // 1024
    int wave = tid >> 6, lane = tid & 63;
    if (tid == 0) { carry_s = 0; row_start[0] = 0; }
    __syncthreads();
    const int CH = 16;
    for (int base = 0; base < n; base += 1024 * CH) {
        int i0 = base + tid * CH;
        int loc[CH];
        int tsum = 0;
#pragma unroll
        for (int q = 0; q < CH; ++q) {
            int idx = i0 + q;
            int v = (idx < n) ? deg[idx] : 0;
            tsum += v;
            loc[q] = tsum;              // inclusive within thread
        }
        int x = tsum;
#pragma unroll
        for (int off = 1; off < 64; off <<= 1) {
            int t = __shfl_up(x, off);
            if (lane >= off) x += t;
        }
        if (lane == 63) wsum[wave] = x;
        __syncthreads();
        if (wave == 0 && lane < 16) {
            int w = wsum[lane];
#pragma unroll
            for (int off = 1; off < 16; off <<= 1) {
                int t = __shfl_up(w, off);
                if (lane >= off) w += t;
            }
            wsum[lane] = w;
        }
        __syncthreads();
        int carry = carry_s;
        int toff = carry + (wave ? wsum[wave - 1] : 0) + (x - tsum);
#pragma unroll
        for (int q = 0; q < CH; ++q) {
            int idx = i0 + q;
            if (idx < n) {
                int excl = toff + (q ? loc[q - 1] : 0);
                row_start[idx + 1] = toff + loc[q];
                cursor[idx] = excl;
            }
        }
        __syncthreads();
        if (tid == 0) carry_s = carry + wsum[15];
        __syncthreads();
    }
}

__global__ void scatter_edges(const int* __restrict__ src, const int* __restrict__ dst,
                              int* __restrict__ cursor, int* __restrict__ srcs, int E) {
    int e = blockIdx.x * blockDim.x + threadIdx.x;
    if (e < E) {
        int p = atomicAdd(&cursor[dst[e]], 1);
        srcs[p] = src[e];
    }
}

// ---------------- merged prep: cast + transposes + projections + count_deg --

__global__ void prep_all(const float* __restrict__ graph, _Float16* __restrict__ Ah, int n4,
                         int cb, int pb,
                         const float* __restrict__ W1, const float* __restrict__ W2,
                         const float* __restrict__ W3,
                         _Float16* __restrict__ Wt1, _Float16* __restrict__ Wt2,
                         _Float16* __restrict__ Bt3,
                         const float* __restrict__ as1, const float* __restrict__ ad1,
                         const float* __restrict__ as2, const float* __restrict__ ad2,
                         const float* __restrict__ as3, const float* __restrict__ ad3,
                         float* __restrict__ wes3, float* __restrict__ wed3,
                         const int* __restrict__ dst, int* __restrict__ deg, int E) {
    int b = blockIdx.x;
    int tid = threadIdx.x;              // 256
    if (b < cb) {                       // ---- cast graph -> f16 ----
        int i = b * 256 + tid;
        if (i < n4) {
            float4 v = ((const float4*)graph)[i];
            half4v o = {(_Float16)v.x, (_Float16)v.y, (_Float16)v.z, (_Float16)v.w};
            ((half4v*)Ah)[i] = o;
        }
        return;
    }
    if (b < cb + 1024) {                // ---- transpose-cast weights ----
        __shared__ float t[32][33];
        int bb = b - cb;
        int region = bb >> 8, idx = bb & 255;
        int r0 = (idx >> 4) * 32, c0 = (idx & 15) * 32;
        const float* in;
        _Float16* out;
        int in_ld, out_ld;
        if (region == 0)      { in = W1;       out = Wt1;       in_ld = 512;  out_ld = 512;  }
        else if (region == 1) { in = W2;       out = Wt2;       in_ld = 512;  out_ld = 512;  }
        else if (region == 2) { in = W3;       out = Bt3;       in_ld = 1024; out_ld = 1024; }
        else                  { in = W3 + 512; out = Bt3 + 512; in_ld = 1024; out_ld = 1024; }
        int tx = tid & 31, ty = tid >> 5;   // 32 x 8
        for (int i = ty; i < 32; i += 8)
            t[i][tx] = in[(size_t)(r0 + i) * in_ld + c0 + tx];
        __syncthreads();
        for (int i = ty; i < 32; i += 8)
            out[(size_t)(c0 + i) * out_ld + r0 + tx] = (_Float16)t[tx][i];
        return;
    }
    if (b >= pb) {                      // ---- count_deg ----
        int e = (b - pb) * 256 + tid;
        if (e < E) atomicAdd(&deg[dst[e]], 1);
        return;
    }
    // ---- attention projections ----
    int w = (b - cb - 1024) * 4 + (tid >> 6);
    int lane = tid & 63;
    if (w < 8192) {                       // Wt1/Wt2 attn rows
        int layer = w >> 12;
        int idx = w & 4095;
        int d = idx & 511, hh = (idx >> 9) & 3, sel = idx >> 11;
        const float* W = layer ? W2 : W1;
        const float* a = layer ? (sel ? ad2 : as2) : (sel ? ad1 : as1);
        const float* row = W + (size_t)d * 512 + hh * 128;
        const float* av = a + hh * 128;
        float s = 0.f;
        s += row[lane] * av[lane];
        s += row[lane + 64] * av[lane + 64];
#pragma unroll
        for (int off = 32; off; off >>= 1) s += __shfl_down(s, off);
        if (lane == 0) {
            _Float16* Wt = layer ? Wt2 : Wt1;
            Wt[(size_t)(512 + sel * 4 + hh) * 512 + d] = (_Float16)s;
        }
    } else if (w < 10240) {               // layer-3 projections
        int idx = w - 8192;
        int k = idx & 511, hh = (idx >> 9) & 1, sel = idx >> 10;
        const float* a = (sel ? ad3 : as3) + hh * 512;
        const float* row = W3 + (size_t)k * 1024 + hh * 512;
        float s = 0.f;
        for (int c = lane; c < 512; c += 64) s += row[c] * a[c];
#pragma unroll
        for (int off = 32; off; off >>= 1) s += __shfl_down(s, off);
        if (lane == 0) (sel ? wed3 : wes3)[hh * 512 + k] = s;
    } else if (w < 11136) {               // zero-fill Wt pad rows 520..575
        int z = (w - 10240) * 64 + lane;
        int layer = z / 28672;
        int rem = z - layer * 28672;
        int row = 520 + rem / 512, col = rem & 511;
        (layer ? Wt2 : Wt1)[(size_t)row * 512 + col] = (_Float16)0.f;
    }
}

// ---------------- MFMA GEMM (layers 1/2: 64x64 tile) -----------------------

#define BK 64

__global__ __launch_bounds__(256) void gemm_f16_att(const _Float16* __restrict__ A,
                                                    const _Float16* __restrict__ Bt,
                                                    _Float16* __restrict__ Hout,
                                                    float* __restrict__ es,
                                                    float* __restrict__ ed,
                                                    int M, int K) {
    __shared__ _Float16 As[64 * BK];
    __shared__ _Float16 Bs[64 * BK];
    int tid = threadIdx.x;
    int lane = tid & 63, wave = tid >> 6;
    int wm = (wave & 1) * 32, wn = (wave >> 1) * 32;
    int m0 = blockIdx.y * 64, n0 = blockIdx.x * 64;
    int l15 = lane & 15, quad = lane >> 4;
    int trow = tid >> 3, tcol = tid & 7;

    floatx4 acc[2][2];
#pragma unroll
    for (int i = 0; i < 2; ++i)
#pragma unroll
        for (int j = 0; j < 2; ++j) acc[i][j] = (floatx4){0.f, 0.f, 0.f, 0.f};

    for (int k0 = 0; k0 < K; k0 += BK) {
        __syncthreads();
#pragma unroll
        for (int i = 0; i < 2; ++i) {
            int gr = m0 + i * 32 + trow; if (gr >= M) gr = M - 1;
            __builtin_amdgcn_global_load_lds(AS1(A + (size_t)gr * K + k0 + tcol * 8),
                                             AS3(As + (size_t)(i * 256 + tid) * 8), 16, 0, 0);
        }
#pragma unroll
        for (int i = 0; i < 2; ++i) {
            int gr = n0 + i * 32 + trow;
            __builtin_amdgcn_global_load_lds(AS1(Bt + (size_t)gr * K + k0 + tcol * 8),
                                             AS3(Bs + (size_t)(i * 256 + tid) * 8), 16, 0, 0);
        }
        __syncthreads();
#pragma unroll
        for (int ks = 0; ks < BK; ks += 32) {
            half8 af[2], bfr[2];
#pragma unroll
            for (int i = 0; i < 2; ++i)
                af[i] = *(const half8*)&As[(wm + i * 16 + l15) * BK + ks + quad * 8];
#pragma unroll
            for (int j = 0; j < 2; ++j)
                bfr[j] = *(const half8*)&Bs[(wn + j * 16 + l15) * BK + ks + quad * 8];
#pragma unroll
            for (int i = 0; i < 2; ++i)
#pragma unroll
                for (int j = 0; j < 2; ++j)
                    acc[i][j] = __builtin_amdgcn_mfma_f32_16x16x32_f16(af[i], bfr[j], acc[i][j], 0, 0, 0);
        }
    }
#pragma unroll
    for (int i = 0; i < 2; ++i)
#pragma unroll
        for (int j = 0; j < 2; ++j) {
            int col = n0 + wn + j * 16 + l15;
#pragma unroll
            for (int r = 0; r < 4; ++r) {
                int row = m0 + wm + i * 16 + quad * 4 + r;
                if (row < M) {
                    float v = acc[i][j][r];
                    if (col < 512) Hout[(size_t)row * 512 + col] = (_Float16)v;
                    else if (col < 516) es[row * 4 + col - 512] = v;
                    else if (col < 520) ed[row * 4 + col - 516] = v;
                }
            }
        }
}

// layer 3: 128x64 tile (acc 2x4 per wave), fp32 out, fused epilogue.
__global__ __launch_bounds__(256) void gemm_f16_ep(const _Float16* __restrict__ A,
                                                   const _Float16* __restrict__ Bt,
                                                   float* __restrict__ out,
                                                   const float* __restrict__ bias,
                                                   const _Float16* __restrict__ xres,
                                                   int M, int Nn, int K) {
    __shared__ _Float16 As[128 * BK];
    __shared__ _Float16 Bs[64 * BK];
    int tid = threadIdx.x;
    int lane = tid & 63, wave = tid >> 6;
    int wm = wave * 32;                     // 4 waves cover 128 rows
    int m0 = blockIdx.y * 128, n0 = blockIdx.x * 64;
    int l15 = lane & 15, quad = lane >> 4;
    int trow = tid >> 3, tcol = tid & 7;

    floatx4 acc[2][4];
#pragma unroll
    for (int i = 0; i < 2; ++i)
#pragma unroll
        for (int j = 0; j < 4; ++j) acc[i][j] = (floatx4){0.f, 0.f, 0.f, 0.f};

    for (int k0 = 0; k0 < K; k0 += BK) {
        __syncthreads();
#pragma unroll
        for (int i = 0; i < 4; ++i) {
            int gr = m0 + i * 32 + trow; if (gr >= M) gr = M - 1;
            __builtin_amdgcn_global_load_lds(AS1(A + (size_t)gr * K + k0 + tcol * 8),
                                             AS3(As + (size_t)(i * 256 + tid) * 8), 16, 0, 0);
        }
#pragma unroll
        for (int i = 0; i < 2; ++i) {
            int gr = n0 + i * 32 + trow;
            __builtin_amdgcn_global_load_lds(AS1(Bt + (size_t)gr * K + k0 + tcol * 8),
                                             AS3(Bs + (size_t)(i * 256 + tid) * 8), 16, 0, 0);
        }
        __syncthreads();
#pragma unroll
        for (int ks = 0; ks < BK; ks += 32) {
            half8 af[2], bfr[4];
#pragma unroll
            for (int i = 0; i < 2; ++i)
                af[i] = *(const half8*)&As[(wm + i * 16 + l15) * BK + ks + quad * 8];
#pragma unroll
            for (int j = 0; j < 4; ++j)
                bfr[j] = *(const half8*)&Bs[(j * 16 + l15) * BK + ks + quad * 8];
#pragma unroll
            for (int i = 0; i < 2; ++i)
#pragma unroll
                for (int j = 0; j < 4; ++j)
                    acc[i][j] = __builtin_amdgcn_mfma_f32_16x16x32_f16(af[i], bfr[j], acc[i][j], 0, 0, 0);
        }
    }
#pragma unroll
    for (int i = 0; i < 2; ++i)
#pragma unroll
        for (int j = 0; j < 4; ++j) {
            int col = n0 + j * 16 + l15;
#pragma unroll
            for (int r = 0; r < 4; ++r) {
                int row = m0 + wm + i * 16 + quad * 4 + r;
                if (row < M)
                    out[(size_t)row * Nn + col] =
                        0.5f * acc[i][j][r] + bias[col] + (float)xres[(size_t)row * Nn + col];
            }
        }
}

// ---------------- aggregation (layers 1/2): 2 waves/node, fused softmax ----
// wave pair: half=0 takes even edges, half=1 odd edges; 4-deep stride-2
// pipeline each; 2-way combine via LDS; even wave does epilogue.

template <bool RES32, bool COEF3>
__global__ __launch_bounds__(512) void aggregate10_concat(
    const _Float16* __restrict__ h, const float* __restrict__ es,
    const float* __restrict__ ed,
    const int* __restrict__ row_start, const int* __restrict__ srcs,
    const float* __restrict__ bias, const float* __restrict__ xres32,
    const _Float16* __restrict__ xres16, _Float16* __restrict__ x_out_h,
    const float* __restrict__ wes3, const float* __restrict__ wed3,
    float* __restrict__ es3, float* __restrict__ ed3, int Nn) {
    __shared__ float part[4][512];
    __shared__ float partden[4][4];
    int wv = threadIdx.x >> 6, lane = threadIdx.x & 63;
    int local = wv >> 1, half = wv & 1;
    int n = blockIdx.x * 4 + local;
    bool active = n < Nn;
    int head = lane >> 4;                 // C=128 -> 16 lanes per head
    int c0 = lane * 8;
    float edn = active ? ed[n * 4 + head] : 0.f;
    int beg = 0, end = 0;
    if (active) { beg = row_start[n]; end = row_start[n + 1]; }
    float acc[8] = {};
    float den = 0.f;
    int j = beg + half;
    for (; j + 6 < end; j += 8) {
        int s0 = srcs[j], s1 = srcs[j + 2], s2 = srcs[j + 4], s3 = srcs[j + 6];
        float e0 = es[s0 * 4 + head], e1 = es[s1 * 4 + head];
        float e2 = es[s2 * 4 + head], e3 = es[s3 * 4 + head];
        half8 h0 = *(const half8*)&h[(size_t)s0 * 512 + c0];
        half8 h1 = *(const half8*)&h[(size_t)s1 * 512 + c0];
        half8 h2 = *(const half8*)&h[(size_t)s2 * 512 + c0];
        half8 h3 = *(const half8*)&h[(size_t)s3 * 512 + c0];
        float w0 = leaky_exp(e0 + edn), w1 = leaky_exp(e1 + edn);
        float w2 = leaky_exp(e2 + edn), w3 = leaky_exp(e3 + edn);
        den += w0 + w1 + w2 + w3;
#pragma unroll
        for (int k = 0; k < 8; ++k) acc[k] += w0 * (float)h0[k];
#pragma unroll
        for (int k = 0; k < 8; ++k) acc[k] += w1 * (float)h1[k];
#pragma unroll
        for (int k = 0; k < 8; ++k) acc[k] += w2 * (float)h2[k];
#pragma unroll
        for (int k = 0; k < 8; ++k) acc[k] += w3 * (float)h3[k];
    }
    for (; j < end; j += 2) {
        int s = srcs[j];
        float w = leaky_exp(es[s * 4 + head] + edn);
        half8 hv = *(const half8*)&h[(size_t)s * 512 + c0];
        den += w;
#pragma unroll
        for (int k = 0; k < 8; ++k) acc[k] += w * (float)hv[k];
    }
    if (half == 1) {
#pragma unroll
        for (int k = 0; k < 8; ++k) part[local][c0 + k] = acc[k];
        if ((lane & 15) == 0) partden[local][head] = den;
    }
    __syncthreads();
    if (half == 0 && active) {
#pragma unroll
        for (int k = 0; k < 8; ++k) acc[k] += part[local][c0 + k];
        den += partden[local][head];
        float invden = 1.f / (den + 1e-16f);
        size_t base = (size_t)n * 512 + c0;
        float v[8];
        half8 o;
#pragma unroll
        for (int k = 0; k < 8; ++k) {
            float res = RES32 ? xres32[base + k] : (float)xres16[base + k];
            float t = acc[k] * invden + bias[c0 + k] + res;
            t = (t > 0.f) ? t : expm1f(t);
            v[k] = t;
            o[k] = (_Float16)t;
        }
        *(half8*)&x_out_h[base] = o;
        if (COEF3) {
            float t0 = 0.f, t1 = 0.f, t2 = 0.f, t3 = 0.f;
#pragma unroll
            for (int k = 0; k < 8; ++k) {
                t0 += v[k] * wes3[c0 + k];
                t1 += v[k] * wes3[512 + c0 + k];
                t2 += v[k] * wed3[c0 + k];
                t3 += v[k] * wed3[512 + c0 + k];
            }
#pragma unroll
            for (int off = 32; off; off >>= 1) {
                t0 += __shfl_down(t0, off);
                t1 += __shfl_down(t1, off);
                t2 += __shfl_down(t2, off);
                t3 += __shfl_down(t3, off);
            }
            if (lane == 0) {
                es3[n * 2] = t0; es3[n * 2 + 1] = t1;
                ed3[n * 2] = t2; ed3[n * 2 + 1] = t3;
            }
        }
    }
}

// ---------------- aggregation (layer 3): 2 waves/node, dual heads ----------

__global__ __launch_bounds__(512) void aggregate10_dual(
    const _Float16* __restrict__ x, const float* __restrict__ es3,
    const float* __restrict__ ed3,
    const int* __restrict__ row_start, const int* __restrict__ srcs,
    _Float16* __restrict__ y, int Nn) {
    __shared__ float part[4][1024];
    __shared__ float partden[4][2];
    int wv = threadIdx.x >> 6, lane = threadIdx.x & 63;
    int local = wv >> 1, half = wv & 1;
    int n = blockIdx.x * 4 + local;
    bool active = n < Nn;
    int c0 = lane * 8;
    float edn0 = 0.f, edn1 = 0.f;
    int beg = 0, end = 0;
    if (active) {
        edn0 = ed3[n * 2]; edn1 = ed3[n * 2 + 1];
        beg = row_start[n]; end = row_start[n + 1];
    }
    float a0[8] = {}, a1[8] = {};
    float den0 = 0.f, den1 = 0.f;
    int j = beg + half;
    for (; j + 6 < end; j += 8) {
        int s0 = srcs[j], s1 = srcs[j + 2], s2 = srcs[j + 4], s3 = srcs[j + 6];
        float2 q0 = *(const float2*)&es3[s0 * 2];
        float2 q1 = *(const float2*)&es3[s1 * 2];
        float2 q2 = *(const float2*)&es3[s2 * 2];
        float2 q3 = *(const float2*)&es3[s3 * 2];
        half8 h0 = *(const half8*)&x[(size_t)s0 * 512 + c0];
        half8 h1 = *(const half8*)&x[(size_t)s1 * 512 + c0];
        half8 h2 = *(const half8*)&x[(size_t)s2 * 512 + c0];
        half8 h3 = *(const half8*)&x[(size_t)s3 * 512 + c0];
        float u0 = leaky_exp(q0.x + edn0), v0 = leaky_exp(q0.y + edn1);
        float u1 = leaky_exp(q1.x + edn0), v1 = leaky_exp(q1.y + edn1);
        float u2 = leaky_exp(q2.x + edn0), v2 = leaky_exp(q2.y + edn1);
        float u3 = leaky_exp(q3.x + edn0), v3 = leaky_exp(q3.y + edn1);
        den0 += u0 + u1 + u2 + u3;
        den1 += v0 + v1 + v2 + v3;
#pragma unroll
        for (int k = 0; k < 8; ++k) { float f = (float)h0[k]; a0[k] += u0 * f; a1[k] += v0 * f; }
#pragma unroll
        for (int k = 0; k < 8; ++k) { float f = (float)h1[k]; a0[k] += u1 * f; a1[k] += v1 * f; }
#pragma unroll
        for (int k = 0; k < 8; ++k) { float f = (float)h2[k]; a0[k] += u2 * f; a1[k] += v2 * f; }
#pragma unroll
        for (int k = 0; k < 8; ++k) { float f = (float)h3[k]; a0[k] += u3 * f; a1[k] += v3 * f; }
    }
    for (; j < end; j += 2) {
        int s = srcs[j];
        float2 q = *(const float2*)&es3[s * 2];
        float u = leaky_exp(q.x + edn0), v = leaky_exp(q.y + edn1);
        half8 hv = *(const half8*)&x[(size_t)s * 512 + c0];
        den0 += u; den1 += v;
#pragma unroll
        for (int k = 0; k < 8; ++k) { float f = (float)hv[k]; a0[k] += u * f; a1[k] += v * f; }
    }
    if (half == 1) {
#pragma unroll
        for (int k = 0; k < 8; ++k) {
            part[local][c0 + k] = a0[k];
            part[local][512 + c0 + k] = a1[k];
        }
        if (lane == 0) { partden[local][0] = den0; partden[local][1] = den1; }
    }
    __syncthreads();
    if (half == 0 && active) {
#pragma unroll
        for (int k = 0; k < 8; ++k) {
            a0[k] += part[local][c0 + k];
            a1[k] += part[local][512 + c0 + k];
        }
        den0 += partden[local][0];
        den1 += partden[local][1];
        float invd0 = 1.f / (den0 + 1e-16f);
        float invd1 = 1.f / (den1 + 1e-16f);
        half8 o0, o1;
#pragma unroll
        for (int k = 0; k < 8; ++k) {
            o0[k] = (_Float16)(a0[k] * invd0);
            o1[k] = (_Float16)(a1[k] * invd1);
        }
        *(half8*)&y[(size_t)n * 1024 + c0] = o0;
        *(half8*)&y[(size_t)n * 1024 + 512 + c0] = o1;
    }
}

// ---------------------------------------------------------------------------

extern "C" void kernel_launch(void* const* d_in, const int* in_sizes, int n_in,
                              void* d_out, int out_size, void* d_ws, size_t ws_size,
                              hipStream_t stream) {
    const float* graph = (const float*)d_in[0];
    const int* edge_index = (const int*)d_in[1];
    const float* W1 = (const float*)d_in[2];
    const float* as1 = (const float*)d_in[3];
    const float* ad1 = (const float*)d_in[4];
    const float* b1 = (const float*)d_in[5];
    const float* W2 = (const float*)d_in[6];
    const float* as2 = (const float*)d_in[7];
    const float* ad2 = (const float*)d_in[8];
    const float* b2 = (const float*)d_in[9];
    const float* W3 = (const float*)d_in[10];
    const float* as3 = (const float*)d_in[11];
    const float* ad3 = (const float*)d_in[12];
    const float* b3 = (const float*)d_in[13];

    const int D = 512;
    int N = in_sizes[0] / D;       // 10000
    int E = in_sizes[1] / 2;       // 160000
    const int* src = edge_index;
    const int* dst = edge_index + E;

    char* p = (char*)d_ws;
    auto carve = [&](size_t bytes) {
        void* r = (void*)p;
        p += (bytes + 255) & ~(size_t)255;
        return r;
    };
    _Float16* Ah   = (_Float16*)carve((size_t)N * 512 * 2);
    _Float16* Wt1  = (_Float16*)carve((size_t)576 * 512 * 2);
    _Float16* Wt2  = (_Float16*)carve((size_t)576 * 512 * 2);
    _Float16* Bt3  = (_Float16*)carve((size_t)512 * 1024 * 2);
    _Float16* h_h  = (_Float16*)carve((size_t)N * 1024 * 2);
    float* es      = (float*)carve((size_t)N * 4 * 4);
    float* ed      = (float*)carve((size_t)N * 4 * 4);
    float* es3     = (float*)carve((size_t)N * 2 * 4);
    float* ed3     = (float*)carve((size_t)N * 2 * 4);
    float* wes3    = (float*)carve((size_t)2 * 512 * 4);
    float* wed3    = (float*)carve((size_t)2 * 512 * 4);
    int* deg       = (int*)carve((size_t)N * 4);
    int* cur       = (int*)carve((size_t)N * 4);
    int* row_st    = (int*)carve((size_t)(N + 1) * 4);
    int* srcs      = (int*)carve((size_t)E * 4);

    // ---- prep (single kernel): cast + transposes + projections + count_deg -
    hipMemsetAsync(deg, 0, (size_t)N * 4, stream);
    int n4 = N * 512 / 4;
    int cb = (n4 + 255) / 256;
    int pb = cb + 1024 + 2784;
    int eb = (E + 255) / 256;
    prep_all<<<pb + eb, 256, 0, stream>>>(
        graph, Ah, n4, cb, pb, W1, W2, W3, Wt1, Wt2, Bt3,
        as1, ad1, as2, ad2, as3, ad3, wes3, wed3, dst, deg, E);

    // ---- CSR (shared by all layers) ----
    scan_kernel<<<1, 1024, 0, stream>>>(deg, row_st, cur, N);
    scatter_edges<<<(E + 255) / 256, 256, 0, stream>>>(src, dst, cur, srcs, E);

    int nblk4 = (N + 3) / 4;
    int mblk = (N + 63) / 64;
    int mblk128 = (N + 127) / 128;
    // ---- Layer 1 ----
    gemm_f16_att<<<dim3(9, mblk), 256, 0, stream>>>(Ah, Wt1, h_h, es, ed, N, 512);
    aggregate10_concat<true, false><<<nblk4, 512, 0, stream>>>(
        h_h, es, ed, row_st, srcs, b1, graph, nullptr, Ah,
        nullptr, nullptr, nullptr, nullptr, N);

    // ---- Layer 2 (also emits layer-3 es3/ed3 in epilogue) ----
    gemm_f16_att<<<dim3(9, mblk), 256, 0, stream>>>(Ah, Wt2, h_h, es, ed, N, 512);
    aggregate10_concat<false, true><<<nblk4, 512, 0, stream>>>(
        h_h, es, ed, row_st, srcs, b2, nullptr, Ah, Ah,
        wes3, wed3, es3, ed3, N);

    // ---- Layer 3: aggregate-then-transform ----
    aggregate10_dual<<<nblk4, 512, 0, stream>>>(Ah, es3, ed3, row_st, srcs, h_h, N);
    gemm_f16_ep<<<dim3(8, mblk128), 256, 0, stream>>>(
        h_h, Bt3, (float*)d_out, b3, Ah, N, 512, 1024);
}